// Round 6
// baseline (274.415 us; speedup 1.0000x reference)
//
#include <hip/hip_runtime.h>

#define NB 8192
#define NH 50
#define ND 64

__device__ __forceinline__ float wsum(float v) {
#pragma unroll
    for (int o = 32; o > 0; o >>= 1) v += __shfl_xor(v, o, 64);
    return v;
}

__device__ __forceinline__ float tanh_fast(float x) {
    const float e = __expf(2.0f * x);
    return (e - 1.0f) * __builtin_amdgcn_rcpf(e + 1.0f);
}

// ---------------- precompute: KW[row] = dot(table[row], Wkey); also zero loss accums ----------------
__global__ __launch_bounds__(256, 8) void kw_kernel(
    const float* __restrict__ t0, const float* __restrict__ t1,
    const float* __restrict__ t2, const float* __restrict__ t3,
    const float* __restrict__ w0, const float* __restrict__ w1,
    const float* __restrict__ w2, const float* __restrict__ w3,
    float* __restrict__ o0, float* __restrict__ o1,
    float* __restrict__ o2, float* __restrict__ o3,
    int r0, int r1, int r2, int r3,
    int b1, int b2, int b3,
    float* __restrict__ out)
{
    if (blockIdx.x == 0 && threadIdx.x == 0) {
        out[4 * NB] = 0.0f;
        out[4 * NB + 1] = 0.0f;
    }
    const int blk = blockIdx.x;
    const float* tab; const float* W; float* o; int rows, base;
    if (blk < b1)      { tab = t0; W = w0; o = o0; rows = r0; base = blk; }
    else if (blk < b2) { tab = t1; W = w1; o = o1; rows = r1; base = blk - b1; }
    else if (blk < b3) { tab = t2; W = w2; o = o2; rows = r2; base = blk - b2; }
    else               { tab = t3; W = w3; o = o3; rows = r3; base = blk - b3; }
    const int lane = threadIdx.x & 63;
    const int wv = threadIdx.x >> 6;
    const int sub = lane >> 4, j = lane & 15;
    const int row = base * 16 + wv * 4 + sub;
    const int rowc = min(row, rows - 1);
    const float4 v = *(const float4*)(tab + (size_t)rowc * ND + j * 4);
    const float4 w = *(const float4*)(W + j * 4);
    float p = v.x * w.x + v.y * w.y + v.z * w.z + v.w * w.w;
    p += __shfl_xor(p, 1, 64);
    p += __shfl_xor(p, 2, 64);
    p += __shfl_xor(p, 4, 64);
    p += __shfl_xor(p, 8, 64);
    if (j == 0 && row < rows) o[row] = p;
}

// ---------------- fwd: one wave per (sample, side); batched gathers for MLP ----------------
__global__ __launch_bounds__(256, 8) void fwd_kernel(
    const int* __restrict__ user1, const int* __restrict__ item1,
    const int* __restrict__ user2, const int* __restrict__ item2,
    const int* __restrict__ u_his, const int* __restrict__ u_pos, const int* __restrict__ u_mask,
    const int* __restrict__ i_his, const int* __restrict__ i_pos, const int* __restrict__ i_mask,
    const float* __restrict__ user1_emb, const float* __restrict__ item1_emb,
    const float* __restrict__ user1_bias, const float* __restrict__ item1_bias,
    const float* __restrict__ u_pos_emb,
    const float* __restrict__ user2_emb, const float* __restrict__ item2_emb,
    const float* __restrict__ user2_bias, const float* __restrict__ item2_bias,
    const float* __restrict__ i_pos_emb,
    const float* __restrict__ attn_u_W, const float* __restrict__ attn_u_b,
    const float* __restrict__ attn_i_W, const float* __restrict__ attn_i_b,
    const float* __restrict__ KWu, const float* __restrict__ KWi,
    const float* __restrict__ PWu, const float* __restrict__ PWi,
    float* __restrict__ out)
{
    const int wave = threadIdx.x >> 6;
    const int d = threadIdx.x & 63;
    const int b = __builtin_amdgcn_readfirstlane(blockIdx.x * 2 + (wave >> 1));
    const bool iw = (wave & 1);  // wave-uniform: false=U-side, true=I-side

    const int iu1 = user1[b], ii1 = item1[b], iu2 = user2[b], ii2 = item2[b];

    const int*   his  = iw ? i_his  : u_his;
    const int*   posa = iw ? i_pos  : u_pos;
    const int*   msk  = iw ? i_mask : u_mask;
    const float* ktab = iw ? user2_emb : item1_emb;
    const float* ptab = iw ? i_pos_emb : u_pos_emb;
    const float* W    = iw ? attn_i_W  : attn_u_W;
    const float  bb   = iw ? attn_i_b[0] : attn_u_b[0];
    const float* KW   = iw ? KWi : KWu;
    const float* PW   = iw ? PWi : PWu;

    const float* qa_tab = iw ? user2_emb : item1_emb;
    const float* qb_tab = iw ? user1_emb : item2_emb;
    const int    qidx   = iw ? iu1 : ii1;
    const float qa = qa_tab[(size_t)qidx * ND + d];
    const float qb = qb_tab[(size_t)qidx * ND + d];

    // epilogue rows: issue gathers NOW, consume after the loop
    const float pa    = iw ? item2_emb[(size_t)ii1 * ND + d] : user1_emb[(size_t)iu1 * ND + d];
    const float add_b = (iw ? item2_emb : item1_emb)[(size_t)ii2 * ND + d];
    const float mul_b = (iw ? user2_emb : user1_emb)[(size_t)iu2 * ND + d];

    const float Wq = W[d];
    const float cq_a = wsum(qa * Wq) + bb;
    const float cq_b = wsum(qb * Wq) + bb;
    const float e0_a = __expf(tanh_fast(cq_a));
    const float e0_b = __expf(tanh_fast(cq_b));

    // lane-parallel slot metadata + scores (lane h owns slot h)
    int hidx = 0, hpos = 0;
    bool act = false;
    if (d < NH) {
        hidx = his[b * NH + d];
        hpos = posa[b * NH + d];
        act  = (msk[b * NH + d] != 0);
    }
    const float s = KW[hidx] + PW[hpos];
    float e_a = 0.0f, e_b = 0.0f;
    if (d < NH) {
        e_a = act ? __expf(tanh_fast(cq_a + s)) : e0_a;
        e_b = act ? __expf(tanh_fast(cq_b + s)) : e0_b;
    }
    const float den_a = wsum(e_a);
    const float den_b = wsum(e_b);

    // ballot compaction of active slots
    const unsigned long long bal = __ballot(act);
    const int nact = __builtin_amdgcn_readfirstlane(__popcll(bal));
    const int below = __builtin_amdgcn_mbcnt_hi(
        (unsigned)(bal >> 32), __builtin_amdgcn_mbcnt_lo((unsigned)bal, 0));
    const int tgt = (act ? below : 63) << 2;
    const int idx_c = __builtin_amdgcn_ds_permute(tgt, hidx);
    const int pos_c = __builtin_amdgcn_ds_permute(tgt, hpos);
    const int ea_c  = __builtin_amdgcn_ds_permute(tgt, __float_as_int(e_a));
    const int eb_c  = __builtin_amdgcn_ds_permute(tgt, __float_as_int(e_b));

    // batched gather loop: 16 slots/batch -> ~32 loads in flight
    float o_a = 0.0f, o_b = 0.0f, reg = 0.0f;
    const int nact16 = (nact + 15) & ~15;
    for (int base = 0; base < nact16; base += 16) {
        int ihs[16], ips[16];
#pragma unroll
        for (int j = 0; j < 16; ++j) {
            const int hc = min(base + j, nact - 1);
            ihs[j] = __builtin_amdgcn_readlane(idx_c, hc);
            ips[j] = __builtin_amdgcn_readlane(pos_c, hc);
        }
        float kvs[16], pvs[16];
#pragma unroll
        for (int j = 0; j < 16; ++j) {
            kvs[j] = ktab[(size_t)ihs[j] * ND + d];
            pvs[j] = ptab[ips[j] * ND + d];
        }
#pragma unroll
        for (int j = 0; j < 16; ++j) {
            const int hh = base + j;
            const int hc = min(hh, nact - 1);
            const bool v = hh < nact;
            const float ea = v ? __int_as_float(__builtin_amdgcn_readlane(ea_c, hc)) : 0.0f;
            const float eb = v ? __int_as_float(__builtin_amdgcn_readlane(eb_c, hc)) : 0.0f;
            const float k = kvs[j] + pvs[j];
            o_a += ea * k;
            o_b += eb * k;
            reg += v ? kvs[j] * kvs[j] : 0.0f;
        }
    }
    o_a *= __builtin_amdgcn_rcpf(den_a);
    o_b *= __builtin_amdgcn_rcpf(den_b);

    // epilogue
    const float add_a = iw ? pa : qa;
    const float mul_a = iw ? qa : pa;
    const float l_a = wsum((o_a + add_a) * mul_a);
    const float l_b = wsum((o_b + add_b) * mul_b);
    const float rv = iw ? (mul_b * mul_b + add_b * add_b) : (mul_a * mul_a + qa * qa);
    const float r = wsum(rv + reg);

    const float* ub = iw ? user2_bias : user1_bias;
    const float* ib = iw ? item2_bias : item1_bias;
    __shared__ float red[4];
    if (d == 0) {
        out[(iw ? NB : 0) + b]          = ub[iu1] + ib[ii1] + l_a;
        out[(iw ? 3 * NB : 2 * NB) + b] = ub[iu2] + ib[ii2] + l_b;
        red[wave] = r;
    }
    __syncthreads();
    if (threadIdx.x == 0)  atomicAdd(&out[4 * NB],     red[0] + red[2]);  // U-waves -> r1
    if (threadIdx.x == 64) atomicAdd(&out[4 * NB + 1], red[1] + red[3]);  // I-waves -> r2
}

// ---------------- fallback path (ws too small for KW tables) ----------------
__global__ void zero_tail_kernel(float* __restrict__ out) {
    out[4 * NB] = 0.0f;
    out[4 * NB + 1] = 0.0f;
}

__global__ __launch_bounds__(256, 8) void fwd_fallback(
    const int* __restrict__ user1, const int* __restrict__ item1,
    const int* __restrict__ user2, const int* __restrict__ item2,
    const int* __restrict__ u_his, const int* __restrict__ u_pos, const int* __restrict__ u_mask,
    const int* __restrict__ i_his, const int* __restrict__ i_pos, const int* __restrict__ i_mask,
    const float* __restrict__ user1_emb, const float* __restrict__ item1_emb,
    const float* __restrict__ user1_bias, const float* __restrict__ item1_bias,
    const float* __restrict__ u_pos_emb,
    const float* __restrict__ user2_emb, const float* __restrict__ item2_emb,
    const float* __restrict__ user2_bias, const float* __restrict__ item2_bias,
    const float* __restrict__ i_pos_emb,
    const float* __restrict__ attn_u_W, const float* __restrict__ attn_u_b,
    const float* __restrict__ attn_i_W, const float* __restrict__ attn_i_b,
    float* __restrict__ out)
{
    const int wave = threadIdx.x >> 6;
    const int d = threadIdx.x & 63;
    const int b = __builtin_amdgcn_readfirstlane(blockIdx.x * 2 + (wave >> 1));
    const bool iw = (wave & 1);

    const int iu1 = user1[b], ii1 = item1[b], iu2 = user2[b], ii2 = item2[b];
    const int*   his  = iw ? i_his  : u_his;
    const int*   posa = iw ? i_pos  : u_pos;
    const int*   msk  = iw ? i_mask : u_mask;
    const float* ktab = iw ? user2_emb : item1_emb;
    const float* ptab = iw ? i_pos_emb : u_pos_emb;
    const float* W    = iw ? attn_i_W  : attn_u_W;
    const float  bb   = iw ? attn_i_b[0] : attn_u_b[0];
    const float* qa_tab = iw ? user2_emb : item1_emb;
    const float* qb_tab = iw ? user1_emb : item2_emb;
    const int    qidx   = iw ? iu1 : ii1;
    const float qa = qa_tab[(size_t)qidx * ND + d];
    const float qb = qb_tab[(size_t)qidx * ND + d];
    const float Wq = W[d], Wk = W[ND + d];
    const float cq_a = wsum(qa * Wq) + bb;
    const float cq_b = wsum(qb * Wq) + bb;

    int hidx = 0, hpos = 0;
    bool act = false;
    if (d < NH) {
        hidx = his[b * NH + d];
        hpos = posa[b * NH + d];
        act  = (msk[b * NH + d] != 0);
    }
    const unsigned long long bal = __ballot(act);
    const int nact = __builtin_amdgcn_readfirstlane(__popcll(bal));
    const int below = __builtin_amdgcn_mbcnt_hi(
        (unsigned)(bal >> 32), __builtin_amdgcn_mbcnt_lo((unsigned)bal, 0));
    const int tgt = (act ? below : 63) << 2;
    const int idx_c = __builtin_amdgcn_ds_permute(tgt, hidx);
    const int pos_c = __builtin_amdgcn_ds_permute(tgt, hpos);

    float o_a = 0.0f, o_b = 0.0f, den_a = 0.0f, den_b = 0.0f, reg = 0.0f;
#pragma unroll 4
    for (int h = 0; h < nact; ++h) {
        const int ih = __builtin_amdgcn_readlane(idx_c, h);
        const int ip = __builtin_amdgcn_readlane(pos_c, h);
        const float kv = ktab[(size_t)ih * ND + d];
        const float pv = ptab[(size_t)ip * ND + d];
        const float k = kv + pv;
        reg += kv * kv;
        const float s = wsum(k * Wk);
        const float ea = __expf(tanh_fast(cq_a + s));
        const float eb = __expf(tanh_fast(cq_b + s));
        o_a += ea * k;  den_a += ea;
        o_b += eb * k;  den_b += eb;
    }
    den_a += (float)(NH - nact) * __expf(tanh_fast(cq_a));
    den_b += (float)(NH - nact) * __expf(tanh_fast(cq_b));
    o_a *= __builtin_amdgcn_rcpf(den_a);
    o_b *= __builtin_amdgcn_rcpf(den_b);

    const float pa = iw ? item2_emb[(size_t)ii1 * ND + d] : user1_emb[(size_t)iu1 * ND + d];
    const float add_a = iw ? pa : qa;
    const float mul_a = iw ? qa : pa;
    const float add_b = (iw ? item2_emb : item1_emb)[(size_t)ii2 * ND + d];
    const float mul_b = (iw ? user2_emb : user1_emb)[(size_t)iu2 * ND + d];
    const float l_a = wsum((o_a + add_a) * mul_a);
    const float l_b = wsum((o_b + add_b) * mul_b);
    const float rv = iw ? (mul_b * mul_b + add_b * add_b) : (mul_a * mul_a + qa * qa);
    const float r = wsum(rv + reg);
    const float* ub = iw ? user2_bias : user1_bias;
    const float* ib = iw ? item2_bias : item1_bias;
    __shared__ float red[4];
    if (d == 0) {
        out[(iw ? NB : 0) + b]          = ub[iu1] + ib[ii1] + l_a;
        out[(iw ? 3 * NB : 2 * NB) + b] = ub[iu2] + ib[ii2] + l_b;
        red[wave] = r;
    }
    __syncthreads();
    if (threadIdx.x == 0)  atomicAdd(&out[4 * NB],     red[0] + red[2]);
    if (threadIdx.x == 64) atomicAdd(&out[4 * NB + 1], red[1] + red[3]);
}

extern "C" void kernel_launch(void* const* d_in, const int* in_sizes, int n_in,
                              void* d_out, int out_size, void* d_ws, size_t ws_size,
                              hipStream_t stream) {
    const int* user1 = (const int*)d_in[0];
    const int* item1 = (const int*)d_in[1];
    const int* user2 = (const int*)d_in[2];
    const int* item2 = (const int*)d_in[3];
    const int* u_his = (const int*)d_in[4];
    const int* u_pos = (const int*)d_in[5];
    const int* u_msk = (const int*)d_in[6];
    const int* i_his = (const int*)d_in[7];
    const int* i_pos = (const int*)d_in[8];
    const int* i_msk = (const int*)d_in[9];
    const float* user1_emb  = (const float*)d_in[10];
    const float* item1_emb  = (const float*)d_in[11];
    const float* user1_bias = (const float*)d_in[12];
    const float* item1_bias = (const float*)d_in[13];
    const float* u_pos_emb  = (const float*)d_in[14];
    const float* user2_emb  = (const float*)d_in[15];
    const float* item2_emb  = (const float*)d_in[16];
    const float* user2_bias = (const float*)d_in[17];
    const float* item2_bias = (const float*)d_in[18];
    const float* i_pos_emb  = (const float*)d_in[19];
    const float* attn_u_W = (const float*)d_in[20];
    const float* attn_u_b = (const float*)d_in[21];
    const float* attn_i_W = (const float*)d_in[22];
    const float* attn_i_b = (const float*)d_in[23];
    float* out = (float*)d_out;
    float* ws  = (float*)d_ws;

    const int I_rows = in_sizes[11] / ND;  // item1_emb rows
    const int U_rows = in_sizes[15] / ND;  // user2_emb rows
    const int P_rows = in_sizes[14] / ND;  // pos table rows

    float* KWu = ws;
    float* KWi = KWu + I_rows;
    float* PWu = KWi + U_rows;
    float* PWi = PWu + 64;
    const size_t need = (size_t)(I_rows + U_rows + 128) * sizeof(float);

    if (ws_size >= need) {
        const int nb0 = (I_rows + 15) / 16;
        const int nb1 = (U_rows + 15) / 16;
        const int nb2 = (P_rows + 15) / 16;
        const int b1 = nb0, b2 = nb0 + nb1, b3 = nb0 + nb1 + nb2;
        const int total = b3 + nb2;
        kw_kernel<<<total, 256, 0, stream>>>(
            item1_emb, user2_emb, u_pos_emb, i_pos_emb,
            attn_u_W + ND, attn_i_W + ND, attn_u_W + ND, attn_i_W + ND,
            KWu, KWi, PWu, PWi,
            I_rows, U_rows, P_rows, P_rows,
            b1, b2, b3, out);
        fwd_kernel<<<NB / 2, 256, 0, stream>>>(
            user1, item1, user2, item2,
            u_his, u_pos, u_msk, i_his, i_pos, i_msk,
            user1_emb, item1_emb, user1_bias, item1_bias, u_pos_emb,
            user2_emb, item2_emb, user2_bias, item2_bias, i_pos_emb,
            attn_u_W, attn_u_b, attn_i_W, attn_i_b,
            KWu, KWi, PWu, PWi,
            out);
    } else {
        zero_tail_kernel<<<1, 1, 0, stream>>>(out);
        fwd_fallback<<<NB / 2, 256, 0, stream>>>(
            user1, item1, user2, item2,
            u_his, u_pos, u_msk, i_his, i_pos, i_msk,
            user1_emb, item1_emb, user1_bias, item1_bias, u_pos_emb,
            user2_emb, item2_emb, user2_bias, item2_bias, i_pos_emb,
            attn_u_W, attn_u_b, attn_i_W, attn_i_b,
            out);
    }
}

// Round 7
// 210.044 us; speedup vs baseline: 1.3065x; 1.3065x over previous
//
#include <hip/hip_runtime.h>

#define NB 8192
#define NH 50
#define ND 64

__device__ __forceinline__ float wsum(float v) {
#pragma unroll
    for (int o = 32; o > 0; o >>= 1) v += __shfl_xor(v, o, 64);
    return v;
}

__device__ __forceinline__ float tanh_fast(float x) {
    const float e = __expf(2.0f * x);
    return (e - 1.0f) * __builtin_amdgcn_rcpf(e + 1.0f);
}

// ---------------- precompute: KW[row] = dot(table[row], Wkey) ----------------
__global__ __launch_bounds__(256, 8) void kw_kernel(
    const float* __restrict__ t0, const float* __restrict__ t1,
    const float* __restrict__ t2, const float* __restrict__ t3,
    const float* __restrict__ w0, const float* __restrict__ w1,
    const float* __restrict__ w2, const float* __restrict__ w3,
    float* __restrict__ o0, float* __restrict__ o1,
    float* __restrict__ o2, float* __restrict__ o3,
    int r0, int r1, int r2, int r3,
    int b1, int b2, int b3)
{
    const int blk = blockIdx.x;
    const float* tab; const float* W; float* o; int rows, base;
    if (blk < b1)      { tab = t0; W = w0; o = o0; rows = r0; base = blk; }
    else if (blk < b2) { tab = t1; W = w1; o = o1; rows = r1; base = blk - b1; }
    else if (blk < b3) { tab = t2; W = w2; o = o2; rows = r2; base = blk - b2; }
    else               { tab = t3; W = w3; o = o3; rows = r3; base = blk - b3; }
    const int lane = threadIdx.x & 63;
    const int wv = threadIdx.x >> 6;
    const int sub = lane >> 4, j = lane & 15;
    const int row = base * 16 + wv * 4 + sub;
    const int rowc = min(row, rows - 1);
    const float4 v = *(const float4*)(tab + (size_t)rowc * ND + j * 4);
    const float4 w = *(const float4*)(W + j * 4);
    float p = v.x * w.x + v.y * w.y + v.z * w.z + v.w * w.w;
    p += __shfl_xor(p, 1, 64);
    p += __shfl_xor(p, 2, 64);
    p += __shfl_xor(p, 4, 64);
    p += __shfl_xor(p, 8, 64);
    if (j == 0 && row < rows) o[row] = p;
}

// ---------------- fwd: one wave per (sample, side); scores via KW/PW gathers ----------------
__global__ __launch_bounds__(256, 8) void fwd_kernel(
    const int* __restrict__ user1, const int* __restrict__ item1,
    const int* __restrict__ user2, const int* __restrict__ item2,
    const int* __restrict__ u_his, const int* __restrict__ u_pos, const int* __restrict__ u_mask,
    const int* __restrict__ i_his, const int* __restrict__ i_pos, const int* __restrict__ i_mask,
    const float* __restrict__ user1_emb, const float* __restrict__ item1_emb,
    const float* __restrict__ user1_bias, const float* __restrict__ item1_bias,
    const float* __restrict__ u_pos_emb,
    const float* __restrict__ user2_emb, const float* __restrict__ item2_emb,
    const float* __restrict__ user2_bias, const float* __restrict__ item2_bias,
    const float* __restrict__ i_pos_emb,
    const float* __restrict__ attn_u_W, const float* __restrict__ attn_u_b,
    const float* __restrict__ attn_i_W, const float* __restrict__ attn_i_b,
    const float* __restrict__ KWu, const float* __restrict__ KWi,
    const float* __restrict__ PWu, const float* __restrict__ PWi,
    float* __restrict__ out, float* __restrict__ ws)
{
    const int wave = threadIdx.x >> 6;
    const int d = threadIdx.x & 63;
    const int b = __builtin_amdgcn_readfirstlane(blockIdx.x * 2 + (wave >> 1));
    const bool iw = (wave & 1);  // wave-uniform: false=U-side, true=I-side

    const int iu1 = user1[b], ii1 = item1[b], iu2 = user2[b], ii2 = item2[b];

    const int*   his  = iw ? i_his  : u_his;
    const int*   posa = iw ? i_pos  : u_pos;
    const int*   msk  = iw ? i_mask : u_mask;
    const float* ktab = iw ? user2_emb : item1_emb;
    const float* ptab = iw ? i_pos_emb : u_pos_emb;
    const float* W    = iw ? attn_i_W  : attn_u_W;
    const float  bb   = iw ? attn_i_b[0] : attn_u_b[0];
    const float* KW   = iw ? KWi : KWu;
    const float* PW   = iw ? PWi : PWu;

    // ---- issue slot metadata + score gathers FIRST (longest chain) ----
    int hidx = 0, hpos = 0;
    bool act = false;
    if (d < NH) {
        hidx = his[b * NH + d];
        hpos = posa[b * NH + d];
        act  = (msk[b * NH + d] != 0);
    }
    const float s = KW[hidx] + PW[hpos];   // lane h owns slot h's raw key score

    // ---- q rows + epilogue rows: issue gathers now, consume later ----
    const float* qa_tab = iw ? user2_emb : item1_emb;
    const float* qb_tab = iw ? user1_emb : item2_emb;
    const int    qidx   = iw ? iu1 : ii1;
    const float qa = qa_tab[(size_t)qidx * ND + d];
    const float qb = qb_tab[(size_t)qidx * ND + d];
    const float pa    = iw ? item2_emb[(size_t)ii1 * ND + d] : user1_emb[(size_t)iu1 * ND + d];
    const float add_b = (iw ? item2_emb : item1_emb)[(size_t)ii2 * ND + d];
    const float mul_b = (iw ? user2_emb : user1_emb)[(size_t)iu2 * ND + d];

    const float Wq = W[d];
    const float cq_a = wsum(qa * Wq) + bb;
    const float cq_b = wsum(qb * Wq) + bb;
    const float e0_a = __expf(tanh_fast(cq_a));
    const float e0_b = __expf(tanh_fast(cq_b));

    float e_a = 0.0f, e_b = 0.0f;
    if (d < NH) {
        e_a = act ? __expf(tanh_fast(cq_a + s)) : e0_a;
        e_b = act ? __expf(tanh_fast(cq_b + s)) : e0_b;
    }
    const float den_a = wsum(e_a);
    const float den_b = wsum(e_b);

    // ballot compaction of active slots
    const unsigned long long bal = __ballot(act);
    const int nact = __builtin_amdgcn_readfirstlane(__popcll(bal));
    const int below = __builtin_amdgcn_mbcnt_hi(
        (unsigned)(bal >> 32), __builtin_amdgcn_mbcnt_lo((unsigned)bal, 0));
    const int tgt = (act ? below : 63) << 2;
    const int idx_c = __builtin_amdgcn_ds_permute(tgt, hidx);
    const int pos_c = __builtin_amdgcn_ds_permute(tgt, hpos);
    const int ea_c  = __builtin_amdgcn_ds_permute(tgt, __float_as_int(e_a));
    const int eb_c  = __builtin_amdgcn_ds_permute(tgt, __float_as_int(e_b));

    // simple gather+FMA loop; unroll 8 -> up to 16 loads in flight, compiler-scheduled
    float o_a = 0.0f, o_b = 0.0f, reg = 0.0f;
#pragma unroll 8
    for (int h = 0; h < nact; ++h) {
        const int ih = __builtin_amdgcn_readlane(idx_c, h);
        const int ip = __builtin_amdgcn_readlane(pos_c, h);
        const float ea = __int_as_float(__builtin_amdgcn_readlane(ea_c, h));
        const float eb = __int_as_float(__builtin_amdgcn_readlane(eb_c, h));
        const float kv = ktab[(size_t)ih * ND + d];
        const float pv = ptab[ip * ND + d];
        const float k = kv + pv;
        o_a += ea * k;
        o_b += eb * k;
        reg += kv * kv;
    }
    o_a *= __builtin_amdgcn_rcpf(den_a);
    o_b *= __builtin_amdgcn_rcpf(den_b);

    // epilogue
    const float add_a = iw ? pa : qa;
    const float mul_a = iw ? qa : pa;
    const float l_a = wsum((o_a + add_a) * mul_a);
    const float l_b = wsum((o_b + add_b) * mul_b);
    const float rv = iw ? (mul_b * mul_b + add_b * add_b) : (mul_a * mul_a + qa * qa);
    const float r = wsum(rv + reg);

    const float* ub = iw ? user2_bias : user1_bias;
    const float* ib = iw ? item2_bias : item1_bias;
    if (d == 0) {
        out[(iw ? NB : 0) + b]          = ub[iu1] + ib[ii1] + l_a;
        out[(iw ? 3 * NB : 2 * NB) + b] = ub[iu2] + ib[ii2] + l_b;
        ws[(iw ? NB : 0) + b] = r;
    }
}

// ---------------- fallback (ws too small for KW tables): round-4 proven kernel ----------------
__global__ __launch_bounds__(256, 8) void fwd_fallback(
    const int* __restrict__ user1, const int* __restrict__ item1,
    const int* __restrict__ user2, const int* __restrict__ item2,
    const int* __restrict__ u_his, const int* __restrict__ u_pos, const int* __restrict__ u_mask,
    const int* __restrict__ i_his, const int* __restrict__ i_pos, const int* __restrict__ i_mask,
    const float* __restrict__ user1_emb, const float* __restrict__ item1_emb,
    const float* __restrict__ user1_bias, const float* __restrict__ item1_bias,
    const float* __restrict__ u_pos_emb,
    const float* __restrict__ user2_emb, const float* __restrict__ item2_emb,
    const float* __restrict__ user2_bias, const float* __restrict__ item2_bias,
    const float* __restrict__ i_pos_emb,
    const float* __restrict__ attn_u_W, const float* __restrict__ attn_u_b,
    const float* __restrict__ attn_i_W, const float* __restrict__ attn_i_b,
    float* __restrict__ out, float* __restrict__ ws)
{
    const int wave = threadIdx.x >> 6;
    const int d = threadIdx.x & 63;
    const int b = __builtin_amdgcn_readfirstlane(blockIdx.x * 2 + (wave >> 1));
    const bool iw = (wave & 1);

    const int iu1 = user1[b], ii1 = item1[b], iu2 = user2[b], ii2 = item2[b];
    const int*   his  = iw ? i_his  : u_his;
    const int*   posa = iw ? i_pos  : u_pos;
    const int*   msk  = iw ? i_mask : u_mask;
    const float* ktab = iw ? user2_emb : item1_emb;
    const float* ptab = iw ? i_pos_emb : u_pos_emb;
    const float* W    = iw ? attn_i_W  : attn_u_W;
    const float  bb   = iw ? attn_i_b[0] : attn_u_b[0];
    const float* qa_tab = iw ? user2_emb : item1_emb;
    const float* qb_tab = iw ? user1_emb : item2_emb;
    const int    qidx   = iw ? iu1 : ii1;
    const float qa = qa_tab[(size_t)qidx * ND + d];
    const float qb = qb_tab[(size_t)qidx * ND + d];
    const float Wq = W[d], Wk = W[ND + d];
    const float cq_a = wsum(qa * Wq) + bb;
    const float cq_b = wsum(qb * Wq) + bb;

    int hidx = 0, hpos = 0;
    bool act = false;
    if (d < NH) {
        hidx = his[b * NH + d];
        hpos = posa[b * NH + d];
        act  = (msk[b * NH + d] != 0);
    }
    const unsigned long long bal = __ballot(act);
    const int nact = __builtin_amdgcn_readfirstlane(__popcll(bal));
    const int below = __builtin_amdgcn_mbcnt_hi(
        (unsigned)(bal >> 32), __builtin_amdgcn_mbcnt_lo((unsigned)bal, 0));
    const int tgt = (act ? below : 63) << 2;
    const int idx_c = __builtin_amdgcn_ds_permute(tgt, hidx);
    const int pos_c = __builtin_amdgcn_ds_permute(tgt, hpos);

    float o_a = 0.0f, o_b = 0.0f, den_a = 0.0f, den_b = 0.0f, reg = 0.0f;
#pragma unroll 4
    for (int h = 0; h < nact; ++h) {
        const int ih = __builtin_amdgcn_readlane(idx_c, h);
        const int ip = __builtin_amdgcn_readlane(pos_c, h);
        const float kv = ktab[(size_t)ih * ND + d];
        const float pv = ptab[(size_t)ip * ND + d];
        const float k = kv + pv;
        reg += kv * kv;
        const float s = wsum(k * Wk);
        const float ea = __expf(tanh_fast(cq_a + s));
        const float eb = __expf(tanh_fast(cq_b + s));
        o_a += ea * k;  den_a += ea;
        o_b += eb * k;  den_b += eb;
    }
    den_a += (float)(NH - nact) * __expf(tanh_fast(cq_a));
    den_b += (float)(NH - nact) * __expf(tanh_fast(cq_b));
    o_a *= __builtin_amdgcn_rcpf(den_a);
    o_b *= __builtin_amdgcn_rcpf(den_b);

    const float pa = iw ? item2_emb[(size_t)ii1 * ND + d] : user1_emb[(size_t)iu1 * ND + d];
    const float add_a = iw ? pa : qa;
    const float mul_a = iw ? qa : pa;
    const float add_b = (iw ? item2_emb : item1_emb)[(size_t)ii2 * ND + d];
    const float mul_b = (iw ? user2_emb : user1_emb)[(size_t)iu2 * ND + d];
    const float l_a = wsum((o_a + add_a) * mul_a);
    const float l_b = wsum((o_b + add_b) * mul_b);
    const float rv = iw ? (mul_b * mul_b + add_b * add_b) : (mul_a * mul_a + qa * qa);
    const float r = wsum(rv + reg);
    const float* ub = iw ? user2_bias : user1_bias;
    const float* ib = iw ? item2_bias : item1_bias;
    if (d == 0) {
        out[(iw ? NB : 0) + b]          = ub[iu1] + ib[ii1] + l_a;
        out[(iw ? 3 * NB : 2 * NB) + b] = ub[iu2] + ib[ii2] + l_b;
        ws[(iw ? NB : 0) + b] = r;
    }
}

__global__ void reduce_kernel(const float* __restrict__ ws, float* __restrict__ out) {
    float a = 0.0f, c = 0.0f;
    for (int i = threadIdx.x; i < NB; i += 256) {
        a += ws[i];
        c += ws[NB + i];
    }
    a = wsum(a);
    c = wsum(c);
    __shared__ float sa[4], sc[4];
    const int w = threadIdx.x >> 6, d = threadIdx.x & 63;
    if (d == 0) { sa[w] = a; sc[w] = c; }
    __syncthreads();
    if (threadIdx.x == 0) {
        out[4 * NB]     = sa[0] + sa[1] + sa[2] + sa[3];
        out[4 * NB + 1] = sc[0] + sc[1] + sc[2] + sc[3];
    }
}

extern "C" void kernel_launch(void* const* d_in, const int* in_sizes, int n_in,
                              void* d_out, int out_size, void* d_ws, size_t ws_size,
                              hipStream_t stream) {
    const int* user1 = (const int*)d_in[0];
    const int* item1 = (const int*)d_in[1];
    const int* user2 = (const int*)d_in[2];
    const int* item2 = (const int*)d_in[3];
    const int* u_his = (const int*)d_in[4];
    const int* u_pos = (const int*)d_in[5];
    const int* u_msk = (const int*)d_in[6];
    const int* i_his = (const int*)d_in[7];
    const int* i_pos = (const int*)d_in[8];
    const int* i_msk = (const int*)d_in[9];
    const float* user1_emb  = (const float*)d_in[10];
    const float* item1_emb  = (const float*)d_in[11];
    const float* user1_bias = (const float*)d_in[12];
    const float* item1_bias = (const float*)d_in[13];
    const float* u_pos_emb  = (const float*)d_in[14];
    const float* user2_emb  = (const float*)d_in[15];
    const float* item2_emb  = (const float*)d_in[16];
    const float* user2_bias = (const float*)d_in[17];
    const float* item2_bias = (const float*)d_in[18];
    const float* i_pos_emb  = (const float*)d_in[19];
    const float* attn_u_W = (const float*)d_in[20];
    const float* attn_u_b = (const float*)d_in[21];
    const float* attn_i_W = (const float*)d_in[22];
    const float* attn_i_b = (const float*)d_in[23];
    float* out = (float*)d_out;
    float* ws  = (float*)d_ws;

    const int I_rows = in_sizes[11] / ND;  // item1_emb rows
    const int U_rows = in_sizes[15] / ND;  // user2_emb rows
    const int P_rows = in_sizes[14] / ND;  // pos table rows

    float* KWu = ws + 2 * NB;
    float* KWi = KWu + I_rows;
    float* PWu = KWi + U_rows;
    float* PWi = PWu + 64;
    const size_t need = (size_t)(2 * NB + I_rows + U_rows + 128) * sizeof(float);

    if (ws_size >= need) {
        const int nb0 = (I_rows + 15) / 16;
        const int nb1 = (U_rows + 15) / 16;
        const int nb2 = (P_rows + 15) / 16;
        const int b1 = nb0, b2 = nb0 + nb1, b3 = nb0 + nb1 + nb2;
        const int total = b3 + nb2;
        kw_kernel<<<total, 256, 0, stream>>>(
            item1_emb, user2_emb, u_pos_emb, i_pos_emb,
            attn_u_W + ND, attn_i_W + ND, attn_u_W + ND, attn_i_W + ND,
            KWu, KWi, PWu, PWi,
            I_rows, U_rows, P_rows, P_rows,
            b1, b2, b3);
        fwd_kernel<<<NB / 2, 256, 0, stream>>>(
            user1, item1, user2, item2,
            u_his, u_pos, u_msk, i_his, i_pos, i_msk,
            user1_emb, item1_emb, user1_bias, item1_bias, u_pos_emb,
            user2_emb, item2_emb, user2_bias, item2_bias, i_pos_emb,
            attn_u_W, attn_u_b, attn_i_W, attn_i_b,
            KWu, KWi, PWu, PWi,
            out, ws);
    } else {
        fwd_fallback<<<NB / 2, 256, 0, stream>>>(
            user1, item1, user2, item2,
            u_his, u_pos, u_msk, i_his, i_pos, i_msk,
            user1_emb, item1_emb, user1_bias, item1_bias, u_pos_emb,
            user2_emb, item2_emb, user2_bias, item2_bias, i_pos_emb,
            attn_u_W, attn_u_b, attn_i_W, attn_i_b,
            out, ws);
    }
    reduce_kernel<<<1, 256, 0, stream>>>(ws, out);
}